// Round 1
// baseline (633.730 us; speedup 1.0000x reference)
//
#include <hip/hip_runtime.h>

#define B_    8
#define CIN_  256
#define CC_   128
#define COUT_ 64
#define H_    64
#define W_    64
#define HP_   68   // padded 64 + 2 + 2
#define KK_   25

// ---- tiny transpose kernels (weights are static per launch) ----

// w_ext[cc][cin][3][3] -> wt[(cin*9+rs)][cc]
__global__ void transpose_wext(const float* __restrict__ w, float* __restrict__ wt) {
    int e = blockIdx.x * 256 + threadIdx.x;           // total 256*9*128 = 294912
    if (e >= CIN_ * 9 * CC_) return;
    int cc = e % CC_;
    int rest = e / CC_;                               // cin*9+rs
    wt[e] = w[cc * (CIN_ * 9) + rest];
}

// w_reg[o][c][25] -> wt[(c*25+k)][o]
__global__ void transpose_wreg(const float* __restrict__ w, float* __restrict__ wt) {
    int e = blockIdx.x * 256 + threadIdx.x;           // total 128*25*64 = 204800
    if (e >= CC_ * KK_ * COUT_) return;
    int o = e % COUT_;
    int rest = e / COUT_;                             // c*25+k
    int k = rest % KK_;
    int c = rest / KK_;
    wt[e] = w[(o * CC_ + c) * KK_ + k];
}

// ---- conv 3x3 (CIN=256 -> CC=128), pad 1, writes into padded f buffer ----
__global__ __launch_bounds__(256) void conv3x3(const float* __restrict__ x,
                                               const float* __restrict__ wt,
                                               const float* __restrict__ bext,
                                               float* __restrict__ fpad) {
    __shared__ float xs[8][10][10];       // 8 cin x (8+2)x(8+2) halo tile
    __shared__ float ws[8 * 9 * 128];     // [ci][rs][cc]
    const int tid = threadIdx.x;
    const int j0 = blockIdx.x * 8, i0 = blockIdx.y * 8, b = blockIdx.z;
    const int cg = tid & 15, pg = tid >> 4;
    const int cc0 = cg * 8;
    const int ri = pg >> 1, rj0 = (pg & 1) * 4;

    float acc[8][4];
#pragma unroll
    for (int c = 0; c < 8; ++c)
#pragma unroll
        for (int p = 0; p < 4; ++p) acc[c][p] = 0.f;

    for (int cin0 = 0; cin0 < CIN_; cin0 += 8) {
        // stage x halo tile
        for (int e = tid; e < 800; e += 256) {
            int ci = e / 100, r = e % 100, ii = r / 10, jj = r % 10;
            int y = i0 - 1 + ii, xx = j0 - 1 + jj;
            float v = 0.f;
            if ((unsigned)y < 64u && (unsigned)xx < 64u)
                v = x[((b * CIN_ + cin0 + ci) * 64 + y) * 64 + xx];
            xs[ci][ii][jj] = v;
        }
        // stage weight chunk (contiguous copy)
        {
            const float* src = wt + cin0 * (9 * CC_);
            for (int e = tid; e < 8 * 9 * 128; e += 256) ws[e] = src[e];
        }
        __syncthreads();

#pragma unroll 1
        for (int ci = 0; ci < 8; ++ci) {
#pragma unroll
            for (int rs = 0; rs < 9; ++rs) {
                const int r = rs / 3, s = rs % 3;
                float4 wa = *(const float4*)&ws[(ci * 9 + rs) * 128 + cc0];
                float4 wb = *(const float4*)&ws[(ci * 9 + rs) * 128 + cc0 + 4];
                float xv[4];
#pragma unroll
                for (int p = 0; p < 4; ++p) xv[p] = xs[ci][ri + r][rj0 + s + p];
#pragma unroll
                for (int p = 0; p < 4; ++p) {
                    acc[0][p] = fmaf(wa.x, xv[p], acc[0][p]);
                    acc[1][p] = fmaf(wa.y, xv[p], acc[1][p]);
                    acc[2][p] = fmaf(wa.z, xv[p], acc[2][p]);
                    acc[3][p] = fmaf(wa.w, xv[p], acc[3][p]);
                    acc[4][p] = fmaf(wb.x, xv[p], acc[4][p]);
                    acc[5][p] = fmaf(wb.y, xv[p], acc[5][p]);
                    acc[6][p] = fmaf(wb.z, xv[p], acc[6][p]);
                    acc[7][p] = fmaf(wb.w, xv[p], acc[7][p]);
                }
            }
        }
        __syncthreads();
    }

#pragma unroll
    for (int c = 0; c < 8; ++c) {
        float bv = bext[cc0 + c];
#pragma unroll
        for (int p = 0; p < 4; ++p) {
            fpad[((b * CC_ + cc0 + c) * HP_ + 2 + i0 + ri) * HP_ + (2 + j0 + rj0 + p)] =
                acc[c][p] + bv;
        }
    }
}

// ---- fused autocorrelation + contraction ----
// out[b,o,i,j] = b_reg[o] + sum_{c,k} w[c,k,o] * f[b,c,i,j] * fpad[b,c,i+u,j+v]
__global__ __launch_bounds__(256) void autocorr(const float* __restrict__ fpad,
                                                const float* __restrict__ wt,
                                                const float* __restrict__ breg,
                                                float* __restrict__ out) {
    __shared__ float ft[8][12][12];        // 8 ch x (8+4)x(8+4) halo tile
    __shared__ float wsh[8 * 25 * 64];     // [ci][k][o]
    const int tid = threadIdx.x;
    const int j0 = blockIdx.x * 8, i0 = blockIdx.y * 8, b = blockIdx.z;
    const int og = tid & 15, pg = tid >> 4;
    const int o0 = og * 4;
    const int ri = pg >> 1, rj0 = (pg & 1) * 4;

    float acc[4][4];
#pragma unroll
    for (int oi = 0; oi < 4; ++oi)
#pragma unroll
        for (int p = 0; p < 4; ++p) acc[oi][p] = 0.f;

    for (int c0 = 0; c0 < CC_; c0 += 8) {
        for (int e = tid; e < 8 * 144; e += 256) {
            int ci = e / 144, r = e % 144, ii = r / 12, jj = r % 12;
            ft[ci][ii][jj] = fpad[((b * CC_ + c0 + ci) * HP_ + i0 + ii) * HP_ + (j0 + jj)];
        }
        {
            const float* src = wt + c0 * (KK_ * COUT_);
            for (int e = tid; e < 8 * 25 * 64; e += 256) wsh[e] = src[e];
        }
        __syncthreads();

#pragma unroll 1
        for (int ci = 0; ci < 8; ++ci) {
            float fc[4];
#pragma unroll
            for (int p = 0; p < 4; ++p) fc[p] = ft[ci][ri + 2][rj0 + 2 + p];
#pragma unroll
            for (int k = 0; k < 25; ++k) {
                const int u = k / 5, v = k % 5;
                float4 w4 = *(const float4*)&wsh[(ci * 25 + k) * 64 + o0];
                float s[4];
#pragma unroll
                for (int p = 0; p < 4; ++p)
                    s[p] = fc[p] * ft[ci][ri + u][rj0 + v + p];
#pragma unroll
                for (int p = 0; p < 4; ++p) {
                    acc[0][p] = fmaf(w4.x, s[p], acc[0][p]);
                    acc[1][p] = fmaf(w4.y, s[p], acc[1][p]);
                    acc[2][p] = fmaf(w4.z, s[p], acc[2][p]);
                    acc[3][p] = fmaf(w4.w, s[p], acc[3][p]);
                }
            }
        }
        __syncthreads();
    }

#pragma unroll
    for (int oi = 0; oi < 4; ++oi) {
        float bv = breg[o0 + oi];
#pragma unroll
        for (int p = 0; p < 4; ++p) {
            out[((b * COUT_ + o0 + oi) * 64 + (i0 + ri)) * 64 + (j0 + rj0 + p)] =
                acc[oi][p] + bv;
        }
    }
}

extern "C" void kernel_launch(void* const* d_in, const int* in_sizes, int n_in,
                              void* d_out, int out_size, void* d_ws, size_t ws_size,
                              hipStream_t stream) {
    const float* x     = (const float*)d_in[0];
    const float* w_ext = (const float*)d_in[1];
    const float* b_ext = (const float*)d_in[2];
    const float* w_reg = (const float*)d_in[3];
    const float* b_reg = (const float*)d_in[4];
    float* out = (float*)d_out;

    char* ws = (char*)d_ws;
    const size_t FPAD_BYTES = (size_t)B_ * CC_ * HP_ * HP_ * 4;        // 18,939,904
    float* fpad   = (float*)ws;
    float* wt_ext = (float*)(ws + FPAD_BYTES);                          // 1,179,648 B
    float* wt_reg = (float*)(ws + FPAD_BYTES + (size_t)CIN_ * 9 * CC_ * 4);

    // zero padded f buffer (pad ring must be 0 every launch)
    hipMemsetAsync(fpad, 0, FPAD_BYTES, stream);

    transpose_wext<<<(CIN_ * 9 * CC_ + 255) / 256, 256, 0, stream>>>(w_ext, wt_ext);
    transpose_wreg<<<(CC_ * KK_ * COUT_ + 255) / 256, 256, 0, stream>>>(w_reg, wt_reg);

    dim3 grid(8, 8, 8);   // (jTiles, iTiles, batch)
    conv3x3<<<grid, 256, 0, stream>>>(x, wt_ext, b_ext, fpad);
    autocorr<<<grid, 256, 0, stream>>>(fpad, wt_reg, b_reg, out);
}

// Round 2
// 438.110 us; speedup vs baseline: 1.4465x; 1.4465x over previous
//
#include <hip/hip_runtime.h>

#define B_    8
#define CIN_  256
#define CC_   128
#define COUT_ 64
#define H_    64
#define W_    64
#define HP_   68   // padded 64 + 2 + 2
#define KK_   25

typedef __attribute__((ext_vector_type(8))) short bh8;
typedef __attribute__((ext_vector_type(4))) float f4;

__device__ __forceinline__ ushort f2bf(float f) {
    uint u = __float_as_uint(f);
    return (ushort)((u + 0x7fffu + ((u >> 16) & 1u)) >> 16);
}

// ---- prep: w_ext fp32 [cc][cin][3][3] -> Wg bf16 [cb 8][rs 9][cc 128][ci 32]
__global__ void prep_wext(const float* __restrict__ w, short* __restrict__ wg) {
    int e = blockIdx.x * 256 + threadIdx.x;
    if (e >= 8 * 9 * 128 * 32) return;
    int ci = e & 31;
    int t  = e >> 5;
    int cc = t & 127;
    int t2 = t >> 7;
    int rs = t2 % 9, cb = t2 / 9;
    float v = w[(cc * CIN_ + cb * 32 + ci) * 9 + rs];
    wg[e] = (short)f2bf(v);
}

// w_reg[o][c][25] -> wt[(c*25+k)][o]  (unchanged fp32 path for autocorr)
__global__ void transpose_wreg(const float* __restrict__ w, float* __restrict__ wt) {
    int e = blockIdx.x * 256 + threadIdx.x;
    if (e >= CC_ * KK_ * COUT_) return;
    int o = e % COUT_;
    int rest = e / COUT_;
    int k = rest % KK_;
    int c = rest / KK_;
    wt[e] = w[(o * CC_ + c) * KK_ + k];
}

// ---- x halo staging: fp32 global -> bf16 LDS tile [10*10 halo px][72-stride ci]
__device__ __forceinline__ void stage_x(const float* __restrict__ x, short* __restrict__ dst,
                                        int b, int cb, int i0, int j0, int tid) {
    for (int e = tid; e < 160; e += 128) {
        int c2 = e & 15, hrow = e >> 4;       // c2: pair of ci, hrow: halo row 0..9
        int ci = cb * 32 + c2 * 2;
        int y = i0 - 1 + hrow;
        const float* xr = x + (((size_t)(b * CIN_ + ci)) * 64 + y) * 64;
        bool yok = (unsigned)y < 64u;
#pragma unroll
        for (int col = 0; col < 10; ++col) {
            int xx = j0 - 1 + col;
            bool ok = yok && ((unsigned)xx < 64u);
            float v0 = ok ? xr[xx] : 0.f;
            float v1 = ok ? xr[64 * 64 + xx] : 0.f;
            uint pk = (uint)f2bf(v0) | ((uint)f2bf(v1) << 16);
            *(uint*)&dst[(hrow * 10 + col) * 72 + c2 * 2] = pk;
        }
    }
}

// ---- conv 3x3 via bf16 MFMA implicit GEMM: f[cc][px] = sum W[cc][k] X[k][px]
__global__ __launch_bounds__(128) void conv3x3_mfma(const float* __restrict__ x,
                                                    const short* __restrict__ wg,
                                                    const float* __restrict__ bext,
                                                    float* __restrict__ fpad) {
    __shared__ __align__(16) short xh[2][100 * 72];   // 28.8 KB double-buffered halo
    const int tid = threadIdx.x;
    const int lane = tid & 63, wv = tid >> 6;         // 2 waves
    const int j0 = blockIdx.x * 8, i0 = blockIdx.y * 8, b = blockIdx.z;
    const int cc0 = wv * 64;
    const int l15 = lane & 15, kg = lane >> 4;

    f4 acc[4][4] = {};

    stage_x(x, xh[0], b, 0, i0, j0, tid);
    __syncthreads();

    for (int cb = 0; cb < 8; ++cb) {
        const int buf = cb & 1;
        if (cb < 7) stage_x(x, xh[buf ^ 1], b, cb + 1, i0, j0, tid);

        const short* wbase = wg + (size_t)(cb * 9) * 128 * 32;
#pragma unroll
        for (int rs = 0; rs < 9; ++rs) {
            const int r = rs / 3, s = rs % 3;
            bh8 a[4], bb[4];
#pragma unroll
            for (int mm = 0; mm < 4; ++mm)
                a[mm] = *(const bh8*)(wbase + (rs * 128 + cc0 + mm * 16 + l15) * 32 + kg * 8);
#pragma unroll
            for (int nn = 0; nn < 4; ++nn) {
                int px = nn * 16 + l15, pi = px >> 3, pj = px & 7;
                int hidx = (pi + r) * 10 + (pj + s);
                bb[nn] = *(const bh8*)&xh[buf][hidx * 72 + kg * 8];
            }
#pragma unroll
            for (int mm = 0; mm < 4; ++mm)
#pragma unroll
                for (int nn = 0; nn < 4; ++nn)
                    acc[mm][nn] = __builtin_amdgcn_mfma_f32_16x16x32_bf16(
                        a[mm], bb[nn], acc[mm][nn], 0, 0, 0);
        }
        __syncthreads();
    }

    // epilogue: D row=(lane>>4)*4+reg -> cc, col=lane&15 -> px  [m89-verified]
#pragma unroll
    for (int mm = 0; mm < 4; ++mm) {
#pragma unroll
        for (int reg = 0; reg < 4; ++reg) {
            int cc = cc0 + mm * 16 + kg * 4 + reg;
            float bv = bext[cc];
#pragma unroll
            for (int nn = 0; nn < 4; ++nn) {
                int px = nn * 16 + l15, pi = px >> 3, pj = px & 7;
                fpad[(((size_t)(b * CC_ + cc)) * HP_ + 2 + i0 + pi) * HP_ + (2 + j0 + pj)] =
                    acc[mm][nn][reg] + bv;
            }
        }
    }
}

// ---- fused autocorrelation + contraction (unchanged fp32) ----
__global__ __launch_bounds__(256) void autocorr(const float* __restrict__ fpad,
                                                const float* __restrict__ wt,
                                                const float* __restrict__ breg,
                                                float* __restrict__ out) {
    __shared__ float ft[8][12][12];
    __shared__ float wsh[8 * 25 * 64];
    const int tid = threadIdx.x;
    const int j0 = blockIdx.x * 8, i0 = blockIdx.y * 8, b = blockIdx.z;
    const int og = tid & 15, pg = tid >> 4;
    const int o0 = og * 4;
    const int ri = pg >> 1, rj0 = (pg & 1) * 4;

    float acc[4][4];
#pragma unroll
    for (int oi = 0; oi < 4; ++oi)
#pragma unroll
        for (int p = 0; p < 4; ++p) acc[oi][p] = 0.f;

    for (int c0 = 0; c0 < CC_; c0 += 8) {
        for (int e = tid; e < 8 * 144; e += 256) {
            int ci = e / 144, r = e % 144, ii = r / 12, jj = r % 12;
            ft[ci][ii][jj] = fpad[((b * CC_ + c0 + ci) * HP_ + i0 + ii) * HP_ + (j0 + jj)];
        }
        {
            const float* src = wt + c0 * (KK_ * COUT_);
            for (int e = tid; e < 8 * 25 * 64; e += 256) wsh[e] = src[e];
        }
        __syncthreads();

#pragma unroll 1
        for (int ci = 0; ci < 8; ++ci) {
            float fc[4];
#pragma unroll
            for (int p = 0; p < 4; ++p) fc[p] = ft[ci][ri + 2][rj0 + 2 + p];
#pragma unroll
            for (int k = 0; k < 25; ++k) {
                const int u = k / 5, v = k % 5;
                float4 w4 = *(const float4*)&wsh[(ci * 25 + k) * 64 + o0];
                float s[4];
#pragma unroll
                for (int p = 0; p < 4; ++p)
                    s[p] = fc[p] * ft[ci][ri + u][rj0 + v + p];
#pragma unroll
                for (int p = 0; p < 4; ++p) {
                    acc[0][p] = fmaf(w4.x, s[p], acc[0][p]);
                    acc[1][p] = fmaf(w4.y, s[p], acc[1][p]);
                    acc[2][p] = fmaf(w4.z, s[p], acc[2][p]);
                    acc[3][p] = fmaf(w4.w, s[p], acc[3][p]);
                }
            }
        }
        __syncthreads();
    }

#pragma unroll
    for (int oi = 0; oi < 4; ++oi) {
        float bv = breg[o0 + oi];
#pragma unroll
        for (int p = 0; p < 4; ++p) {
            out[((b * COUT_ + o0 + oi) * 64 + (i0 + ri)) * 64 + (j0 + rj0 + p)] =
                acc[oi][p] + bv;
        }
    }
}

extern "C" void kernel_launch(void* const* d_in, const int* in_sizes, int n_in,
                              void* d_out, int out_size, void* d_ws, size_t ws_size,
                              hipStream_t stream) {
    const float* x     = (const float*)d_in[0];
    const float* w_ext = (const float*)d_in[1];
    const float* b_ext = (const float*)d_in[2];
    const float* w_reg = (const float*)d_in[3];
    const float* b_reg = (const float*)d_in[4];
    float* out = (float*)d_out;

    char* ws = (char*)d_ws;
    const size_t FPAD_BYTES = (size_t)B_ * CC_ * HP_ * HP_ * 4;   // 18,939,904
    const size_t WG_BYTES   = (size_t)8 * 9 * 128 * 32 * 2;       // 589,824
    float* fpad   = (float*)ws;
    short* wgq    = (short*)(ws + FPAD_BYTES);
    float* wt_reg = (float*)(ws + FPAD_BYTES + WG_BYTES);

    hipMemsetAsync(fpad, 0, FPAD_BYTES, stream);

    prep_wext<<<(8 * 9 * 128 * 32 + 255) / 256, 256, 0, stream>>>(w_ext, wgq);
    transpose_wreg<<<(CC_ * KK_ * COUT_ + 255) / 256, 256, 0, stream>>>(w_reg, wt_reg);

    dim3 cgrid(8, 8, 8);
    conv3x3_mfma<<<cgrid, 128, 0, stream>>>(x, wgq, b_ext, fpad);
    autocorr<<<cgrid, 256, 0, stream>>>(fpad, wt_reg, b_reg, out);
}

// Round 3
// 143.000 us; speedup vs baseline: 4.4317x; 3.0637x over previous
//
#include <hip/hip_runtime.h>
#include <hip/hip_bf16.h>

#define B_    8
#define CIN_  256
#define CC_   128
#define COUT_ 64
#define HP_   68            // padded 64 + 2 + 2
#define HPX_  (HP_ * HP_)   // 4624

typedef __attribute__((ext_vector_type(8))) short bh8;
typedef __attribute__((ext_vector_type(4))) float f4;

__device__ __forceinline__ ushort f2bf(float f) {   // RNE, int-ops
    uint u = __float_as_uint(f);
    return (ushort)((u + 0x7fffu + ((u >> 16) & 1u)) >> 16);
}
__device__ __forceinline__ float bf2f(ushort s) {
    return __uint_as_float(((uint)s) << 16);
}
__device__ __forceinline__ short f2bf_c(float f) {  // compiler path -> v_cvt_pk fusion
    __hip_bfloat16 h = __float2bfloat16(f);
    short s;
    __builtin_memcpy(&s, &h, 2);
    return s;
}

// ---- prep: w_ext fp32 [cc][cin][3][3] -> bf16 [cb 8][rs 9][cc 128][ci 32]
__global__ void prep_wext(const float* __restrict__ w, short* __restrict__ wg) {
    int e = blockIdx.x * 256 + threadIdx.x;
    if (e >= 8 * 9 * 128 * 32) return;
    int ci = e & 31;
    int t  = e >> 5;
    int cc = t & 127;
    int t2 = t >> 7;
    int rs = t2 % 9, cb = t2 / 9;
    wg[e] = (short)f2bf(w[(cc * CIN_ + cb * 32 + ci) * 9 + rs]);
}

// ---- prep: w_reg fp32 [o][c][25] -> bf16 wA[q 4][k 25][o 64][ci 32]
__global__ void prep_wA(const float* __restrict__ w, short* __restrict__ wa) {
    int e = blockIdx.x * 256 + threadIdx.x;
    if (e >= 4 * 25 * 64 * 32) return;
    int ci = e & 31;
    int o  = (e >> 5) & 63;
    int rest = e >> 11;          // q*25 + k
    int k = rest % 25, q = rest / 25;
    wa[e] = (short)f2bf(w[(o * CC_ + q * 32 + ci) * 25 + k]);
}

// ---- x halo staging: fp32 global -> bf16 LDS tile [10*10 halo px][72-stride ci]
__device__ __forceinline__ void stage_x(const float* __restrict__ x, short* __restrict__ dst,
                                        int b, int cb, int i0, int j0, int tid) {
    for (int e = tid; e < 160; e += 128) {
        int c2 = e & 15, hrow = e >> 4;
        int ci = cb * 32 + c2 * 2;
        int y = i0 - 1 + hrow;
        const float* xr = x + (((size_t)(b * CIN_ + ci)) * 64 + y) * 64;
        bool yok = (unsigned)y < 64u;
#pragma unroll
        for (int col = 0; col < 10; ++col) {
            int xx = j0 - 1 + col;
            bool ok = yok && ((unsigned)xx < 64u);
            float v0 = ok ? xr[xx] : 0.f;
            float v1 = ok ? xr[64 * 64 + xx] : 0.f;
            uint pk = (uint)f2bf(v0) | ((uint)f2bf(v1) << 16);
            *(uint*)&dst[(hrow * 10 + col) * 72 + c2 * 2] = pk;
        }
    }
}

// ---- conv 3x3 bf16 MFMA; writes f as bf16 TRANSPOSED: fpad_t[b][hpx(68x68)][128c]
__global__ __launch_bounds__(128) void conv3x3_mfma(const float* __restrict__ x,
                                                    const short* __restrict__ wg,
                                                    const float* __restrict__ bext,
                                                    ushort* __restrict__ fpad_t) {
    __shared__ __align__(16) short xh[2][100 * 72];
    const int tid = threadIdx.x;
    const int lane = tid & 63, wv = tid >> 6;
    const int j0 = blockIdx.x * 8, i0 = blockIdx.y * 8, b = blockIdx.z;
    const int cc0 = wv * 64;
    const int l15 = lane & 15, kg = lane >> 4;

    f4 acc[4][4] = {};

    stage_x(x, xh[0], b, 0, i0, j0, tid);
    __syncthreads();

    for (int cb = 0; cb < 8; ++cb) {
        const int buf = cb & 1;
        if (cb < 7) stage_x(x, xh[buf ^ 1], b, cb + 1, i0, j0, tid);

        const short* wbase = wg + (size_t)(cb * 9) * 128 * 32;
#pragma unroll
        for (int rs = 0; rs < 9; ++rs) {
            const int r = rs / 3, s = rs % 3;
            bh8 a[4], bb[4];
#pragma unroll
            for (int mm = 0; mm < 4; ++mm)
                a[mm] = *(const bh8*)(wbase + (rs * 128 + cc0 + mm * 16 + l15) * 32 + kg * 8);
#pragma unroll
            for (int nn = 0; nn < 4; ++nn) {
                int px = nn * 16 + l15, pi = px >> 3, pj = px & 7;
                int hidx = (pi + r) * 10 + (pj + s);
                bb[nn] = *(const bh8*)&xh[buf][hidx * 72 + kg * 8];
            }
#pragma unroll
            for (int mm = 0; mm < 4; ++mm)
#pragma unroll
                for (int nn = 0; nn < 4; ++nn)
                    acc[mm][nn] = __builtin_amdgcn_mfma_f32_16x16x32_bf16(
                        a[mm], bb[nn], acc[mm][nn], 0, 0, 0);
        }
        __syncthreads();
    }

    // epilogue: D row -> cc, col -> px; pack 4 consecutive cc as 2x u32, store 8B
#pragma unroll
    for (int mm = 0; mm < 4; ++mm) {
        const int ccb = cc0 + mm * 16 + kg * 4;
        float bv0 = bext[ccb + 0], bv1 = bext[ccb + 1];
        float bv2 = bext[ccb + 2], bv3 = bext[ccb + 3];
#pragma unroll
        for (int nn = 0; nn < 4; ++nn) {
            int px = nn * 16 + l15, pi = px >> 3, pj = px & 7;
            size_t row = ((size_t)b * HPX_ + (2 + i0 + pi) * HP_ + (2 + j0 + pj)) * 128;
            uint lo = (uint)f2bf(acc[mm][nn][0] + bv0) | ((uint)f2bf(acc[mm][nn][1] + bv1) << 16);
            uint hi = (uint)f2bf(acc[mm][nn][2] + bv2) | ((uint)f2bf(acc[mm][nn][3] + bv3) << 16);
            uint2 pk; pk.x = lo; pk.y = hi;
            *(uint2*)&fpad_t[row + ccb] = pk;
        }
    }
}

// ---- autocorr via bf16 MFMA: out[o,px] = sum_{q,k} A(w)[o,K] * B(g)[K,px]
// B built on the fly: g = f_center * f_shift, both from LDS f-tile.
__global__ __launch_bounds__(128) void autocorr_mfma(const ushort* __restrict__ ft,
                                                     const short* __restrict__ wA,
                                                     const float* __restrict__ breg,
                                                     float* __restrict__ out) {
    __shared__ __align__(16) short flds[144 * 136];   // [12x12 halo px][136-stride c] bf16
    const int tid = threadIdx.x;
    const int lane = tid & 63, wv = tid >> 6;         // 2 waves, split px (n)
    const int j0 = blockIdx.x * 8, i0 = blockIdx.y * 8, b = blockIdx.z;
    const int l15 = lane & 15, kg = lane >> 4;

    // stage whole f halo tile: 144 px x 128 ch bf16 (contiguous b128 copies)
    for (int e = tid; e < 2304; e += 128) {
        int hp = e >> 4, seg = e & 15;
        int hr = hp / 12, hc = hp - hr * 12;
        const ushort* src = ft + ((size_t)b * HPX_ + (i0 + hr) * HP_ + (j0 + hc)) * 128 + seg * 8;
        *(bh8*)&flds[hp * 136 + seg * 8] = *(const bh8*)src;
    }
    __syncthreads();

    f4 acc[4][2] = {};
    int base_off[2], cen_off[2];
#pragma unroll
    for (int t = 0; t < 2; ++t) {
        int px = (wv * 2 + t) * 16 + l15;
        int pi = px >> 3, pj = px & 7;
        base_off[t] = (pi * 12 + pj) * 136 + kg * 8;
        cen_off[t]  = ((pi + 2) * 12 + (pj + 2)) * 136 + kg * 8;
    }

#pragma unroll 1
    for (int q = 0; q < 4; ++q) {                     // channel chunks of 32
        float cen[2][8];
#pragma unroll
        for (int t = 0; t < 2; ++t) {
            bh8 c8 = *(const bh8*)&flds[cen_off[t] + q * 32];
#pragma unroll
            for (int jj = 0; jj < 8; ++jj) cen[t][jj] = bf2f((ushort)c8[jj]);
        }
        const short* wq = wA + q * (25 * 64 * 32);
#pragma unroll
        for (int k = 0; k < 25; ++k) {                // 5x5 shifts, unrolled: imm offsets
            const int u = k / 5, v = k % 5;
            const int koff = (u * 12 + v) * 136;
            bh8 a[4];
#pragma unroll
            for (int mm = 0; mm < 4; ++mm)
                a[mm] = *(const bh8*)(wq + (k * 64 + mm * 16 + l15) * 32 + kg * 8);
            bh8 bb[2];
#pragma unroll
            for (int t = 0; t < 2; ++t) {
                bh8 s8 = *(const bh8*)&flds[base_off[t] + q * 32 + koff];
#pragma unroll
                for (int jj = 0; jj < 8; ++jj) {
                    float p = bf2f((ushort)s8[jj]) * cen[t][jj];
                    bb[t][jj] = f2bf_c(p);
                }
            }
#pragma unroll
            for (int mm = 0; mm < 4; ++mm)
#pragma unroll
                for (int t = 0; t < 2; ++t)
                    acc[mm][t] = __builtin_amdgcn_mfma_f32_16x16x32_bf16(
                        a[mm], bb[t], acc[mm][t], 0, 0, 0);
        }
    }

    // epilogue: D row -> o, col -> px
#pragma unroll
    for (int mm = 0; mm < 4; ++mm) {
#pragma unroll
        for (int reg = 0; reg < 4; ++reg) {
            int o = mm * 16 + kg * 4 + reg;
            float bv = breg[o];
#pragma unroll
            for (int t = 0; t < 2; ++t) {
                int px = (wv * 2 + t) * 16 + l15, pi = px >> 3, pj = px & 7;
                out[(((size_t)(b * COUT_ + o)) * 64 + i0 + pi) * 64 + j0 + pj] =
                    acc[mm][t][reg] + bv;
            }
        }
    }
}

extern "C" void kernel_launch(void* const* d_in, const int* in_sizes, int n_in,
                              void* d_out, int out_size, void* d_ws, size_t ws_size,
                              hipStream_t stream) {
    const float* x     = (const float*)d_in[0];
    const float* w_ext = (const float*)d_in[1];
    const float* b_ext = (const float*)d_in[2];
    const float* w_reg = (const float*)d_in[3];
    const float* b_reg = (const float*)d_in[4];
    float* out = (float*)d_out;

    char* ws = (char*)d_ws;
    const size_t FPADT_BYTES = (size_t)B_ * HPX_ * 128 * 2;   // 9,469,952
    const size_t WG_BYTES    = (size_t)8 * 9 * 128 * 32 * 2;  // 589,824
    ushort* fpad_t = (ushort*)ws;
    short*  wgq    = (short*)(ws + FPADT_BYTES);
    short*  wa     = (short*)(ws + FPADT_BYTES + WG_BYTES);

    // zero padded ring (and interior; conv overwrites interior)
    hipMemsetAsync(fpad_t, 0, FPADT_BYTES, stream);

    prep_wext<<<(8 * 9 * 128 * 32 + 255) / 256, 256, 0, stream>>>(w_ext, wgq);
    prep_wA<<<(4 * 25 * 64 * 32 + 255) / 256, 256, 0, stream>>>(w_reg, wa);

    dim3 grid(8, 8, 8);
    conv3x3_mfma<<<grid, 128, 0, stream>>>(x, wgq, b_ext, fpad_t);
    autocorr_mfma<<<grid, 128, 0, stream>>>(fpad_t, wa, b_reg, out);
}

// Round 4
// 88.402 us; speedup vs baseline: 7.1687x; 1.6176x over previous
//
#include <hip/hip_runtime.h>
#include <hip/hip_bf16.h>

#define B_    8
#define CIN_  256
#define CC_   128
#define COUT_ 64
#define HP_   68            // f padded: 64 + 2 + 2
#define HPX_  (HP_ * HP_)   // 4624
#define XQW_  66            // x padded: 64 + 1 + 1
#define XQPX_ (XQW_ * XQW_) // 4356

typedef __attribute__((ext_vector_type(8))) short bh8;
typedef __attribute__((ext_vector_type(4))) float f4;

__device__ __forceinline__ ushort f2bf(float f) {   // RNE
    uint u = __float_as_uint(f);
    return (ushort)((u + 0x7fffu + ((u >> 16) & 1u)) >> 16);
}
__device__ __forceinline__ float bf2f(ushort s) {
    return __uint_as_float(((uint)s) << 16);
}
__device__ __forceinline__ short f2bf_c(float f) {  // compiler path -> v_cvt_pk fusion
    __hip_bfloat16 h = __float2bfloat16(f);
    short s;
    __builtin_memcpy(&s, &h, 2);
    return s;
}

// ---- prep: x fp32 [b][256ci][64][64] -> bf16 xq[b][cb 8][66][66][32ci], zero ring
__global__ __launch_bounds__(256) void prep_x(const float* __restrict__ x,
                                              ushort* __restrict__ xq) {
    __shared__ float xt[2][32][65];   // [row-pair][ci][xx] (65: bank-spread)
    const int tid = threadIdx.x;
    const int rp = blockIdx.x, cb = blockIdx.y, b = blockIdx.z;

#pragma unroll
    for (int rr = 0; rr < 2; ++rr) {
        int y = rp * 2 + rr - 1;
        if ((unsigned)y < 64u) {
            int xx = tid & 63, wv = tid >> 6;
#pragma unroll
            for (int it = 0; it < 8; ++it) {
                int ci = it * 4 + wv;
                xt[rr][ci][xx] = x[(((size_t)(b * CIN_ + cb * 32 + ci)) * 64 + y) * 64 + xx];
            }
        }
    }
    __syncthreads();

    for (int e = tid; e < 528; e += 256) {           // 2 rows x 66 hc x 4 segs
        int rr = e / 264, t = e - rr * 264;
        int hc = t >> 2, seg = t & 3;
        int y = rp * 2 + rr - 1, xx = hc - 1;
        uint pk[4] = {0u, 0u, 0u, 0u};
        if ((unsigned)y < 64u && (unsigned)xx < 64u) {
#pragma unroll
            for (int i = 0; i < 4; ++i) {
                uint lo = f2bf(xt[rr][seg * 8 + i * 2][xx]);
                uint hi = f2bf(xt[rr][seg * 8 + i * 2 + 1][xx]);
                pk[i] = lo | (hi << 16);
            }
        }
        uint4 v; v.x = pk[0]; v.y = pk[1]; v.z = pk[2]; v.w = pk[3];
        *(uint4*)&xq[((((size_t)(b * 8 + cb)) * XQPX_) + (rp * 2 + rr) * XQW_ + hc) * 32 + seg * 8] = v;
    }
}

// ---- prep: w_ext fp32 [cc][cin][3][3] -> bf16 [cb 8][rs 9][cc 128][ci 32]
__global__ void prep_wext(const float* __restrict__ w, short* __restrict__ wg) {
    int e = blockIdx.x * 256 + threadIdx.x;
    if (e >= 8 * 9 * 128 * 32) return;
    int ci = e & 31;
    int t  = e >> 5;
    int cc = t & 127;
    int t2 = t >> 7;
    int rs = t2 % 9, cb = t2 / 9;
    wg[e] = (short)f2bf(w[(cc * CIN_ + cb * 32 + ci) * 9 + rs]);
}

// ---- prep: w_reg fp32 [o][c][25] -> bf16 wA[q 4][k 25][o 64][ci 32]
__global__ void prep_wA(const float* __restrict__ w, short* __restrict__ wa) {
    int e = blockIdx.x * 256 + threadIdx.x;
    if (e >= 4 * 25 * 64 * 32) return;
    int ci = e & 31;
    int o  = (e >> 5) & 63;
    int rest = e >> 11;
    int k = rest % 25, q = rest / 25;
    wa[e] = (short)f2bf(w[(o * CC_ + q * 32 + ci) * 25 + k]);
}

// ---- conv staging: pure b128 copies from xq (halo (i0-1..i0+8) -> xq rows i0..i0+9)
__device__ __forceinline__ void stage_xq(const ushort* __restrict__ xq, short* __restrict__ dst,
                                         int b, int cb, int i0, int j0, int tid) {
    const ushort* base = xq + (((size_t)(b * 8 + cb)) * XQPX_) * 32;
    for (int e = tid; e < 400; e += 256) {           // 100 hpx x 4 segs of 8ci
        int hp = e >> 2, seg = e & 3;
        int hr = hp / 10, hc = hp - hr * 10;
        const ushort* src = base + ((size_t)((i0 + hr) * XQW_ + (j0 + hc))) * 32 + seg * 8;
        *(bh8*)&dst[hp * 72 + seg * 8] = *(const bh8*)src;
    }
}

// ---- conv 3x3 bf16 MFMA; 4 waves: wave = 32cc x 64px (m=2, n=4)
__global__ __launch_bounds__(256) void conv3x3_mfma(const ushort* __restrict__ xq,
                                                    const short* __restrict__ wg,
                                                    const float* __restrict__ bext,
                                                    ushort* __restrict__ fpad_t) {
    __shared__ __align__(16) short xh[2][100 * 72];   // 28.8 KB double-buffered
    const int tid = threadIdx.x;
    const int lane = tid & 63, wv = tid >> 6;
    const int j0 = blockIdx.x * 8, i0 = blockIdx.y * 8, b = blockIdx.z;
    const int l15 = lane & 15, kg = lane >> 4;
    const int cc0 = wv * 32;

    f4 acc[2][4] = {};

    stage_xq(xq, xh[0], b, 0, i0, j0, tid);
    __syncthreads();

    for (int cb = 0; cb < 8; ++cb) {
        const int buf = cb & 1;
        if (cb < 7) stage_xq(xq, xh[buf ^ 1], b, cb + 1, i0, j0, tid);

        const short* wbase = wg + (size_t)(cb * 9) * 128 * 32;
#pragma unroll
        for (int rs = 0; rs < 9; ++rs) {
            const int r = rs / 3, s = rs % 3;
            bh8 a[2], bb[4];
#pragma unroll
            for (int mm = 0; mm < 2; ++mm)
                a[mm] = *(const bh8*)(wbase + (rs * 128 + cc0 + mm * 16 + l15) * 32 + kg * 8);
#pragma unroll
            for (int nn = 0; nn < 4; ++nn) {
                int px = nn * 16 + l15, pi = px >> 3, pj = px & 7;
                int hidx = (pi + r) * 10 + (pj + s);
                bb[nn] = *(const bh8*)&xh[buf][hidx * 72 + kg * 8];
            }
#pragma unroll
            for (int mm = 0; mm < 2; ++mm)
#pragma unroll
                for (int nn = 0; nn < 4; ++nn)
                    acc[mm][nn] = __builtin_amdgcn_mfma_f32_16x16x32_bf16(
                        a[mm], bb[nn], acc[mm][nn], 0, 0, 0);
        }
        __syncthreads();
    }

    // epilogue: D row -> cc (kg*4+reg), col -> px; pack 4 cc -> 8B store
#pragma unroll
    for (int mm = 0; mm < 2; ++mm) {
        const int ccb = cc0 + mm * 16 + kg * 4;
        float bv0 = bext[ccb + 0], bv1 = bext[ccb + 1];
        float bv2 = bext[ccb + 2], bv3 = bext[ccb + 3];
#pragma unroll
        for (int nn = 0; nn < 4; ++nn) {
            int px = nn * 16 + l15, pi = px >> 3, pj = px & 7;
            size_t row = (size_t)b * HPX_ + (2 + i0 + pi) * HP_ + (2 + j0 + pj);
            uint lo = (uint)f2bf(acc[mm][nn][0] + bv0) | ((uint)f2bf(acc[mm][nn][1] + bv1) << 16);
            uint hi = (uint)f2bf(acc[mm][nn][2] + bv2) | ((uint)f2bf(acc[mm][nn][3] + bv3) << 16);
            uint2 pk; pk.x = lo; pk.y = hi;
            *(uint2*)&fpad_t[row * 128 + ccb] = pk;
        }
    }
}

// ---- autocorr bf16 MFMA; 4 waves: wave = 32o x 32px (m=2, n=2; oh/ph split)
__global__ __launch_bounds__(256) void autocorr_mfma(const ushort* __restrict__ ft,
                                                     const short* __restrict__ wA,
                                                     const float* __restrict__ breg,
                                                     float* __restrict__ out) {
    __shared__ __align__(16) short flds[144 * 136];   // 39.2 KB
    const int tid = threadIdx.x;
    const int lane = tid & 63, wv = tid >> 6;
    const int oh = wv >> 1, ph = wv & 1;
    const int j0 = blockIdx.x * 8, i0 = blockIdx.y * 8, b = blockIdx.z;
    const int l15 = lane & 15, kg = lane >> 4;

    for (int e = tid; e < 2304; e += 256) {           // 144 hpx x 16 segs
        int hp = e >> 4, seg = e & 15;
        int hr = hp / 12, hc = hp - hr * 12;
        const ushort* src = ft + ((size_t)b * HPX_ + (i0 + hr) * HP_ + (j0 + hc)) * 128 + seg * 8;
        *(bh8*)&flds[hp * 136 + seg * 8] = *(const bh8*)src;
    }
    __syncthreads();

    f4 acc[2][2] = {};
    int base_off[2], cen_off[2];
#pragma unroll
    for (int t = 0; t < 2; ++t) {
        int px = ph * 32 + t * 16 + l15;
        int pi = px >> 3, pj = px & 7;
        base_off[t] = (pi * 12 + pj) * 136 + kg * 8;
        cen_off[t]  = ((pi + 2) * 12 + (pj + 2)) * 136 + kg * 8;
    }

#pragma unroll 1
    for (int q = 0; q < 4; ++q) {
        float cen[2][8];
#pragma unroll
        for (int t = 0; t < 2; ++t) {
            bh8 c8 = *(const bh8*)&flds[cen_off[t] + q * 32];
#pragma unroll
            for (int jj = 0; jj < 8; ++jj) cen[t][jj] = bf2f((ushort)c8[jj]);
        }
        const short* wq = wA + q * (25 * 64 * 32);
#pragma unroll
        for (int k = 0; k < 25; ++k) {
            const int u = k / 5, v = k % 5;
            const int koff = (u * 12 + v) * 136;
            bh8 a[2];
#pragma unroll
            for (int mm = 0; mm < 2; ++mm)
                a[mm] = *(const bh8*)(wq + (k * 64 + oh * 32 + mm * 16 + l15) * 32 + kg * 8);
            bh8 bb[2];
#pragma unroll
            for (int t = 0; t < 2; ++t) {
                bh8 s8 = *(const bh8*)&flds[base_off[t] + q * 32 + koff];
#pragma unroll
                for (int jj = 0; jj < 8; ++jj) {
                    float p = bf2f((ushort)s8[jj]) * cen[t][jj];
                    bb[t][jj] = f2bf_c(p);
                }
            }
#pragma unroll
            for (int mm = 0; mm < 2; ++mm)
#pragma unroll
                for (int t = 0; t < 2; ++t)
                    acc[mm][t] = __builtin_amdgcn_mfma_f32_16x16x32_bf16(
                        a[mm], bb[t], acc[mm][t], 0, 0, 0);
        }
    }

    // epilogue: D row -> o, col -> px
#pragma unroll
    for (int mm = 0; mm < 2; ++mm) {
#pragma unroll
        for (int reg = 0; reg < 4; ++reg) {
            int o = oh * 32 + mm * 16 + kg * 4 + reg;
            float bv = breg[o];
#pragma unroll
            for (int t = 0; t < 2; ++t) {
                int px = ph * 32 + t * 16 + l15, pi = px >> 3, pj = px & 7;
                out[(((size_t)(b * COUT_ + o)) * 64 + i0 + pi) * 64 + j0 + pj] =
                    acc[mm][t][reg] + bv;
            }
        }
    }
}

extern "C" void kernel_launch(void* const* d_in, const int* in_sizes, int n_in,
                              void* d_out, int out_size, void* d_ws, size_t ws_size,
                              hipStream_t stream) {
    const float* x     = (const float*)d_in[0];
    const float* w_ext = (const float*)d_in[1];
    const float* b_ext = (const float*)d_in[2];
    const float* w_reg = (const float*)d_in[3];
    const float* b_reg = (const float*)d_in[4];
    float* out = (float*)d_out;

    char* ws = (char*)d_ws;
    const size_t FPADT_BYTES = (size_t)B_ * HPX_ * 128 * 2;        // 9,469,952
    const size_t WG_BYTES    = (size_t)8 * 9 * 128 * 32 * 2;       // 589,824
    const size_t WA_BYTES    = (size_t)4 * 25 * 64 * 32 * 2;       // 409,600
    ushort* fpad_t = (ushort*)ws;
    short*  wgq    = (short*)(ws + FPADT_BYTES);
    short*  wa     = (short*)(ws + FPADT_BYTES + WG_BYTES);
    ushort* xq     = (ushort*)(ws + FPADT_BYTES + WG_BYTES + WA_BYTES);  // 17,842,176

    hipMemsetAsync(fpad_t, 0, FPADT_BYTES, stream);   // pad ring must be zero

    dim3 pgrid(33, 8, 8);                             // row-pairs, cb, b
    prep_x<<<pgrid, 256, 0, stream>>>(x, xq);
    prep_wext<<<(8 * 9 * 128 * 32 + 255) / 256, 256, 0, stream>>>(w_ext, wgq);
    prep_wA<<<(4 * 25 * 64 * 32 + 255) / 256, 256, 0, stream>>>(w_reg, wa);

    dim3 grid(8, 8, 8);
    conv3x3_mfma<<<grid, 256, 0, stream>>>(xq, wgq, b_ext, fpad_t);
    autocorr_mfma<<<grid, 256, 0, stream>>>(fpad_t, wa, b_reg, out);
}

// Round 5
// 86.955 us; speedup vs baseline: 7.2880x; 1.0166x over previous
//
#include <hip/hip_runtime.h>
#include <hip/hip_bf16.h>

#define B_    8
#define CIN_  256
#define CC_   128
#define COUT_ 64
#define HP_   68            // f padded: 64 + 2 + 2
#define HPX_  (HP_ * HP_)   // 4624
#define XQW_  66            // x padded: 64 + 1 + 1
#define XQPX_ (XQW_ * XQW_) // 4356

typedef __attribute__((ext_vector_type(8))) short bh8;
typedef __attribute__((ext_vector_type(4))) float f4;

__device__ __forceinline__ ushort f2bf(float f) {   // RNE
    uint u = __float_as_uint(f);
    return (ushort)((u + 0x7fffu + ((u >> 16) & 1u)) >> 16);
}
__device__ __forceinline__ float bf2f(ushort s) {
    return __uint_as_float(((uint)s) << 16);
}
__device__ __forceinline__ short f2bf_c(float f) {  // compiler path -> v_cvt_pk fusion
    __hip_bfloat16 h = __float2bfloat16(f);
    short s;
    __builtin_memcpy(&s, &h, 2);
    return s;
}

// ---- zero only the 2-wide pad ring of fpad_t (interior is overwritten by conv)
// ring px per b: rows {0,1,66,67} x 68  +  rows 2..65 x cols {0,1,66,67} = 528
__global__ __launch_bounds__(256) void zero_ring(ushort* __restrict__ fpad_t) {
    int e = blockIdx.x * 256 + threadIdx.x;           // total 8*528*16 = 67584
    if (e >= 8 * 528 * 16) return;
    int seg = e & 15;
    int t = e >> 4;
    int b = t / 528, rp = t - b * 528;
    int i, j;
    if (rp < 136) { i = rp / 68; j = rp - (rp / 68) * 68; }
    else if (rp < 272) { int r = rp - 136; i = 66 + r / 68; j = r - (r / 68) * 68; }
    else { int r = rp - 272; i = 2 + (r >> 2); int c = r & 3; j = (c < 2) ? c : c + 64; }
    uint4 z; z.x = 0u; z.y = 0u; z.z = 0u; z.w = 0u;
    *(uint4*)&fpad_t[(((size_t)b * HPX_) + i * HP_ + j) * 128 + seg * 8] = z;
}

// ---- prep: x fp32 [b][256ci][64][64] -> bf16 xq[b][cb 8][66][66][32ci], zero ring
__global__ __launch_bounds__(256) void prep_x(const float* __restrict__ x,
                                              ushort* __restrict__ xq) {
    __shared__ float xt[2][32][65];   // [row-pair][ci][xx] (65: bank-spread)
    const int tid = threadIdx.x;
    const int rp = blockIdx.x, cb = blockIdx.y, b = blockIdx.z;

#pragma unroll
    for (int rr = 0; rr < 2; ++rr) {
        int y = rp * 2 + rr - 1;
        if ((unsigned)y < 64u) {
            int xx = tid & 63, wv = tid >> 6;
#pragma unroll
            for (int it = 0; it < 8; ++it) {
                int ci = it * 4 + wv;
                xt[rr][ci][xx] = x[(((size_t)(b * CIN_ + cb * 32 + ci)) * 64 + y) * 64 + xx];
            }
        }
    }
    __syncthreads();

    for (int e = tid; e < 528; e += 256) {           // 2 rows x 66 hc x 4 segs
        int rr = e / 264, t = e - rr * 264;
        int hc = t >> 2, seg = t & 3;
        int y = rp * 2 + rr - 1, xx = hc - 1;
        uint pk[4] = {0u, 0u, 0u, 0u};
        if ((unsigned)y < 64u && (unsigned)xx < 64u) {
#pragma unroll
            for (int i = 0; i < 4; ++i) {
                uint lo = f2bf(xt[rr][seg * 8 + i * 2][xx]);
                uint hi = f2bf(xt[rr][seg * 8 + i * 2 + 1][xx]);
                pk[i] = lo | (hi << 16);
            }
        }
        uint4 v; v.x = pk[0]; v.y = pk[1]; v.z = pk[2]; v.w = pk[3];
        *(uint4*)&xq[((((size_t)(b * 8 + cb)) * XQPX_) + (rp * 2 + rr) * XQW_ + hc) * 32 + seg * 8] = v;
    }
}

// ---- prep: w_ext fp32 [cc][cin][3][3] -> bf16 [cb 8][rs 9][cc 128][ci 32]
__global__ void prep_wext(const float* __restrict__ w, short* __restrict__ wg) {
    int e = blockIdx.x * 256 + threadIdx.x;
    if (e >= 8 * 9 * 128 * 32) return;
    int ci = e & 31;
    int t  = e >> 5;
    int cc = t & 127;
    int t2 = t >> 7;
    int rs = t2 % 9, cb = t2 / 9;
    wg[e] = (short)f2bf(w[(cc * CIN_ + cb * 32 + ci) * 9 + rs]);
}

// ---- prep: w_reg fp32 [o][c][25] -> bf16 wA[q 4][k 25][o 64][ci 32]
__global__ void prep_wA(const float* __restrict__ w, short* __restrict__ wa) {
    int e = blockIdx.x * 256 + threadIdx.x;
    if (e >= 4 * 25 * 64 * 32) return;
    int ci = e & 31;
    int o  = (e >> 5) & 63;
    int rest = e >> 11;
    int k = rest % 25, q = rest / 25;
    wa[e] = (short)f2bf(w[(o * CC_ + q * 32 + ci) * 25 + k]);
}

// ---- conv staging: pure b128 copies from xq
__device__ __forceinline__ void stage_xq(const ushort* __restrict__ xq, short* __restrict__ dst,
                                         int b, int cb, int i0, int j0, int tid) {
    const ushort* base = xq + (((size_t)(b * 8 + cb)) * XQPX_) * 32;
    for (int e = tid; e < 400; e += 256) {           // 100 hpx x 4 segs of 8ci
        int hp = e >> 2, seg = e & 3;
        int hr = hp / 10, hc = hp - hr * 10;
        const ushort* src = base + ((size_t)((i0 + hr) * XQW_ + (j0 + hc))) * 32 + seg * 8;
        *(bh8*)&dst[hp * 72 + seg * 8] = *(const bh8*)src;
    }
}

// ---- conv 3x3 bf16 MFMA; 4 waves: wave = 32cc x 64px (m=2, n=4)
__global__ __launch_bounds__(256) void conv3x3_mfma(const ushort* __restrict__ xq,
                                                    const short* __restrict__ wg,
                                                    const float* __restrict__ bext,
                                                    ushort* __restrict__ fpad_t) {
    __shared__ __align__(16) short xh[2][100 * 72];   // 28.8 KB double-buffered
    const int tid = threadIdx.x;
    const int lane = tid & 63, wv = tid >> 6;
    const int j0 = blockIdx.x * 8, i0 = blockIdx.y * 8, b = blockIdx.z;
    const int l15 = lane & 15, kg = lane >> 4;
    const int cc0 = wv * 32;

    f4 acc[2][4] = {};

    stage_xq(xq, xh[0], b, 0, i0, j0, tid);
    __syncthreads();

    for (int cb = 0; cb < 8; ++cb) {
        const int buf = cb & 1;
        if (cb < 7) stage_xq(xq, xh[buf ^ 1], b, cb + 1, i0, j0, tid);

        const short* wbase = wg + (size_t)(cb * 9) * 128 * 32;
#pragma unroll
        for (int rs = 0; rs < 9; ++rs) {
            const int r = rs / 3, s = rs % 3;
            bh8 a[2], bb[4];
#pragma unroll
            for (int mm = 0; mm < 2; ++mm)
                a[mm] = *(const bh8*)(wbase + (rs * 128 + cc0 + mm * 16 + l15) * 32 + kg * 8);
#pragma unroll
            for (int nn = 0; nn < 4; ++nn) {
                int px = nn * 16 + l15, pi = px >> 3, pj = px & 7;
                int hidx = (pi + r) * 10 + (pj + s);
                bb[nn] = *(const bh8*)&xh[buf][hidx * 72 + kg * 8];
            }
#pragma unroll
            for (int mm = 0; mm < 2; ++mm)
#pragma unroll
                for (int nn = 0; nn < 4; ++nn)
                    acc[mm][nn] = __builtin_amdgcn_mfma_f32_16x16x32_bf16(
                        a[mm], bb[nn], acc[mm][nn], 0, 0, 0);
        }
        __syncthreads();
    }

    // epilogue: D row -> cc (kg*4+reg), col -> px; pack 4 cc -> 8B store
#pragma unroll
    for (int mm = 0; mm < 2; ++mm) {
        const int ccb = cc0 + mm * 16 + kg * 4;
        float bv0 = bext[ccb + 0], bv1 = bext[ccb + 1];
        float bv2 = bext[ccb + 2], bv3 = bext[ccb + 3];
#pragma unroll
        for (int nn = 0; nn < 4; ++nn) {
            int px = nn * 16 + l15, pi = px >> 3, pj = px & 7;
            size_t row = (size_t)b * HPX_ + (2 + i0 + pi) * HP_ + (2 + j0 + pj);
            uint lo = (uint)f2bf(acc[mm][nn][0] + bv0) | ((uint)f2bf(acc[mm][nn][1] + bv1) << 16);
            uint hi = (uint)f2bf(acc[mm][nn][2] + bv2) | ((uint)f2bf(acc[mm][nn][3] + bv3) << 16);
            uint2 pk; pk.x = lo; pk.y = hi;
            *(uint2*)&fpad_t[row * 128 + ccb] = pk;
        }
    }
}

// ---- autocorr bf16 MFMA; 4 waves: wave = 32o x 32px (m=2, n=2; oh/ph split)
__global__ __launch_bounds__(256) void autocorr_mfma(const ushort* __restrict__ ft,
                                                     const short* __restrict__ wA,
                                                     const float* __restrict__ breg,
                                                     float* __restrict__ out) {
    __shared__ __align__(16) short flds[144 * 136];   // 39.2 KB
    const int tid = threadIdx.x;
    const int lane = tid & 63, wv = tid >> 6;
    const int oh = wv >> 1, ph = wv & 1;
    const int j0 = blockIdx.x * 8, i0 = blockIdx.y * 8, b = blockIdx.z;
    const int l15 = lane & 15, kg = lane >> 4;

    for (int e = tid; e < 2304; e += 256) {           // 144 hpx x 16 segs
        int hp = e >> 4, seg = e & 15;
        int hr = hp / 12, hc = hp - hr * 12;
        const ushort* src = ft + ((size_t)b * HPX_ + (i0 + hr) * HP_ + (j0 + hc)) * 128 + seg * 8;
        *(bh8*)&flds[hp * 136 + seg * 8] = *(const bh8*)src;
    }
    __syncthreads();

    f4 acc[2][2] = {};
    int base_off[2], cen_off[2];
#pragma unroll
    for (int t = 0; t < 2; ++t) {
        int px = ph * 32 + t * 16 + l15;
        int pi = px >> 3, pj = px & 7;
        base_off[t] = (pi * 12 + pj) * 136 + kg * 8;
        cen_off[t]  = ((pi + 2) * 12 + (pj + 2)) * 136 + kg * 8;
    }

#pragma unroll 1
    for (int q = 0; q < 4; ++q) {
        float cen[2][8];
#pragma unroll
        for (int t = 0; t < 2; ++t) {
            bh8 c8 = *(const bh8*)&flds[cen_off[t] + q * 32];
#pragma unroll
            for (int jj = 0; jj < 8; ++jj) cen[t][jj] = bf2f((ushort)c8[jj]);
        }
        const short* wq = wA + q * (25 * 64 * 32);
#pragma unroll
        for (int k = 0; k < 25; ++k) {
            const int u = k / 5, v = k % 5;
            const int koff = (u * 12 + v) * 136;
            bh8 a[2];
#pragma unroll
            for (int mm = 0; mm < 2; ++mm)
                a[mm] = *(const bh8*)(wq + (k * 64 + oh * 32 + mm * 16 + l15) * 32 + kg * 8);
            bh8 bb[2];
#pragma unroll
            for (int t = 0; t < 2; ++t) {
                bh8 s8 = *(const bh8*)&flds[base_off[t] + q * 32 + koff];
#pragma unroll
                for (int jj = 0; jj < 8; ++jj) {
                    float p = bf2f((ushort)s8[jj]) * cen[t][jj];
                    bb[t][jj] = f2bf_c(p);
                }
            }
#pragma unroll
            for (int mm = 0; mm < 2; ++mm)
#pragma unroll
                for (int t = 0; t < 2; ++t)
                    acc[mm][t] = __builtin_amdgcn_mfma_f32_16x16x32_bf16(
                        a[mm], bb[t], acc[mm][t], 0, 0, 0);
        }
    }

    // epilogue: D row -> o, col -> px
#pragma unroll
    for (int mm = 0; mm < 2; ++mm) {
#pragma unroll
        for (int reg = 0; reg < 4; ++reg) {
            int o = oh * 32 + mm * 16 + kg * 4 + reg;
            float bv = breg[o];
#pragma unroll
            for (int t = 0; t < 2; ++t) {
                int px = ph * 32 + t * 16 + l15, pi = px >> 3, pj = px & 7;
                out[(((size_t)(b * COUT_ + o)) * 64 + i0 + pi) * 64 + j0 + pj] =
                    acc[mm][t][reg] + bv;
            }
        }
    }
}

extern "C" void kernel_launch(void* const* d_in, const int* in_sizes, int n_in,
                              void* d_out, int out_size, void* d_ws, size_t ws_size,
                              hipStream_t stream) {
    const float* x     = (const float*)d_in[0];
    const float* w_ext = (const float*)d_in[1];
    const float* b_ext = (const float*)d_in[2];
    const float* w_reg = (const float*)d_in[3];
    const float* b_reg = (const float*)d_in[4];
    float* out = (float*)d_out;

    char* ws = (char*)d_ws;
    const size_t FPADT_BYTES = (size_t)B_ * HPX_ * 128 * 2;        // 9,469,952
    const size_t WG_BYTES    = (size_t)8 * 9 * 128 * 32 * 2;       // 589,824
    const size_t WA_BYTES    = (size_t)4 * 25 * 64 * 32 * 2;       // 409,600
    ushort* fpad_t = (ushort*)ws;
    short*  wgq    = (short*)(ws + FPADT_BYTES);
    short*  wa     = (short*)(ws + FPADT_BYTES + WG_BYTES);
    ushort* xq     = (ushort*)(ws + FPADT_BYTES + WG_BYTES + WA_BYTES);  // 17,842,176

    zero_ring<<<(8 * 528 * 16 + 255) / 256, 256, 0, stream>>>(fpad_t);

    dim3 pgrid(33, 8, 8);                             // row-pairs, cb, b
    prep_x<<<pgrid, 256, 0, stream>>>(x, xq);
    prep_wext<<<(8 * 9 * 128 * 32 + 255) / 256, 256, 0, stream>>>(w_ext, wgq);
    prep_wA<<<(4 * 25 * 64 * 32 + 255) / 256, 256, 0, stream>>>(w_reg, wa);

    dim3 grid(8, 8, 8);
    conv3x3_mfma<<<grid, 256, 0, stream>>>(xq, wgq, b_ext, fpad_t);
    autocorr_mfma<<<grid, 256, 0, stream>>>(fpad_t, wa, b_reg, out);
}